// Round 6
// baseline (101.880 us; speedup 1.0000x reference)
//
#include <hip/hip_runtime.h>
#include <math.h>

#define S_GRID   112
#define BATCH_N  64
#define NBOX     100
#define SS       (S_GRID * S_GRID)       // 12544 cells per image
#define NCELLS   (BATCH_N * SS)          // 802816
#define CELLSZ   (1.0f / (float)S_GRID)
#define BLK      256
#define CH       7                       // chunks per block
#define BPI      7                       // blocks per image (7*7*256 = 12544)
#define NBLK     (BATCH_N * BPI)         // 448 blocks
#define PSTRIDE  21                      // 20 floats + 1 pad (gcd(21,32)=1, conflict-free)
#define HITW     (SS / 32)               // 392 words of hit bitmap

// ---------- device helpers ----------

__device__ __forceinline__ float iou_fn(float px, float py, float pw, float ph,
                                        float gx, float gy, float gw, float gh) {
    // matches reference _iou (eps = 1e-6)
    float px1 = px - pw * 0.5f, px2 = px + pw * 0.5f;
    float py1 = py - ph * 0.5f, py2 = py + ph * 0.5f;
    float gx1 = gx - gw * 0.5f, gx2 = gx + gw * 0.5f;
    float gy1 = gy - gh * 0.5f, gy2 = gy + gh * 0.5f;
    float iw = fmaxf(fminf(px2, gx2) - fmaxf(px1, gx1), 0.f);
    float ih = fmaxf(fminf(py2, gy2) - fmaxf(py1, gy1), 0.f);
    float inter = iw * ih;
    float ap = fmaxf(px2 - px1, 0.f) * fmaxf(py2 - py1, 0.f);
    float ag = fmaxf(gx2 - gx1, 0.f) * fmaxf(gy2 - gy1, 0.f);
    float uni = ap + ag - inter;
    return inter / (uni + 1e-6f);
}

__device__ __forceinline__ float ciou_fn(float px, float py, float pw, float ph,
                                         float gx, float gy, float gw, float gh) {
    // matches reference _ciou (eps = 1e-7)
    const float eps = 1e-7f;
    float px1 = px - pw * 0.5f, px2 = px + pw * 0.5f;
    float py1 = py - ph * 0.5f, py2 = py + ph * 0.5f;
    float gx1 = gx - gw * 0.5f, gx2 = gx + gw * 0.5f;
    float gy1 = gy - gh * 0.5f, gy2 = gy + gh * 0.5f;
    float iw = fmaxf(fminf(px2, gx2) - fmaxf(px1, gx1), 0.f);
    float ih = fmaxf(fminf(py2, gy2) - fmaxf(py1, gy1), 0.f);
    float inter = iw * ih;
    float ap = fmaxf(px2 - px1, 0.f) * fmaxf(py2 - py1, 0.f);
    float ag = fmaxf(gx2 - gx1, 0.f) * fmaxf(gy2 - gy1, 0.f);
    float uni = ap + ag - inter;
    float iou = inter / (uni + eps);
    float dx = px - gx, dy = py - gy;
    float rho2 = dx * dx + dy * dy;
    float cw = fmaxf(px2, gx2) - fminf(px1, gx1);
    float ch = fmaxf(py2, gy2) - fminf(py1, gy1);
    float c2 = cw * cw + ch * ch + eps;
    float dv = atanf(gw / (gh + eps)) - atanf(pw / (ph + eps));
    float v = 0.40528473456935109f * dv * dv;   // 4/pi^2
    float alpha = v / (1.f - iou + v + eps);
    return 1.f - iou + rho2 / c2 + alpha * v;
}

__device__ __forceinline__ float focal_fn(float logit, float t) {
    float bce = fmaxf(logit, 0.f) - logit * t + log1pf(expf(-fabsf(logit)));
    float p = 1.f / (1.f + expf(-logit));
    float p_t = t * p + (1.f - t) * (1.f - p);
    float a_t = t * 0.25f + (1.f - t) * 0.75f;
    float om = 1.f - p_t;
    return a_t * om * om * bce;
}

// ---------- kernel 1: persistent per-cell loss (7 chunks per block) ----------
// 448 blocks (7/image), each loops over 7 chunks of 256 cells with a
// register->LDS pipeline: prefetch chunk k+1's float4s while consuming chunk k.
// Tables for the image's 100 targets built once per block.

__global__ __launch_bounds__(BLK, 2) void loss_kernel(const float* __restrict__ pred,
                                                      const float* __restrict__ tgt,
                                                      float* __restrict__ partial) {
    __shared__ float    sp[BLK * PSTRIDE];   // staged preds, padded rows (21504 B)
    __shared__ int      s_cell[NBOX];        // image-local cell id per box (-1 invalid)
    __shared__ float4   s_box[NBOX];         // cx, cy, w, h
    __shared__ unsigned s_cbit[NBOX];        // class bit
    __shared__ unsigned s_hit[HITW];         // per-cell "has any box" bitmap
    __shared__ float    sred[BLK / 64];

    const int bid = blockIdx.x, tid = threadIdx.x;
    const int img = bid / BPI;
    const int sec = bid - img * BPI;

    // float4 base of this block's first chunk
    const float4* src = (const float4*)(pred + (size_t)img * SS * 20)
                        + (size_t)sec * CH * BLK * 5;

    // prefetch chunk 0
    float4 r0 = src[tid];
    float4 r1 = src[tid + BLK];
    float4 r2 = src[tid + 2 * BLK];
    float4 r3 = src[tid + 3 * BLK];
    float4 r4 = src[tid + 4 * BLK];

    // zero hit bitmap
    if (tid < HITW) s_hit[tid] = 0u;
    if (tid + BLK < HITW) s_hit[tid + BLK] = 0u;
    __syncthreads();

    // box table (threads 0..99), once per block
    if (tid < NBOX) {
        const float* t = tgt + ((size_t)img * NBOX + tid) * 5;
        float t0 = t[0], cx = t[1], cy = t[2], w = t[3], h = t[4];
        int cellid = -1; unsigned cb = 0u;
        if (t0 >= 0.f) {
            int cls = min(max((int)t0, 0), 9);
            int col = min(max((int)(cx * (float)S_GRID), 0), S_GRID - 1);
            int row = min(max((int)(cy * (float)S_GRID), 0), S_GRID - 1);
            cellid = row * S_GRID + col;
            cb = 1u << cls;
            atomicOr(&s_hit[cellid >> 5], 1u << (cellid & 31));
        }
        s_cell[tid] = cellid;
        s_box[tid]  = make_float4(cx, cy, w, h);
        s_cbit[tid] = cb;
    }

    float acc = 0.f;

    for (int k = 0; k < CH; ++k) {
        if (k) __syncthreads();              // prior chunk's consumers done
        // scatter regs into padded LDS rows
#define WR(j, vv) { int i = tid + (j) * BLK; float* d = &sp[(i / 5) * PSTRIDE + (i % 5) * 4]; \
                    d[0] = vv.x; d[1] = vv.y; d[2] = vv.z; d[3] = vv.w; }
        WR(0, r0) WR(1, r1) WR(2, r2) WR(3, r3) WR(4, r4)
#undef WR
        __syncthreads();

        // issue next chunk's loads early (overlap with consume)
        if (k + 1 < CH) {
            const float4* s2 = src + (size_t)(k + 1) * BLK * 5;
            r0 = s2[tid];
            r1 = s2[tid + BLK];
            r2 = s2[tid + 2 * BLK];
            r3 = s2[tid + 3 * BLK];
            r4 = s2[tid + 4 * BLK];
        }

        // consume chunk k
        const int rc = (sec * CH + k) * BLK + tid;   // cell id within image
        const float* P = &sp[tid * PSTRIDE];
        float conf0 = P[4], conf1 = P[9];

        bool hit = (s_hit[rc >> 5] >> (rc & 31)) & 1u;
        if (!hit) {
            acc += 0.1f * (conf0 * conf0 + conf1 * conf1);
        } else {
            float colf = (float)(rc % S_GRID);
            float rowf = (float)(rc / S_GRID);

            // ascending scan, strict '>' == reference (max iou, smallest index)
            unsigned mask = 0u; float bestv = -1.f; int jwin = 0, bj = 0;
            for (int j = 0; j < NBOX; ++j) {
                if (s_cell[j] == rc) {
                    mask |= s_cbit[j];
                    float4 g = s_box[j];
                    float dx0 = (P[0] + colf) * CELLSZ, dy0 = (P[1] + rowf) * CELLSZ;
                    float i0 = iou_fn(dx0, dy0, P[2], P[3], g.x, g.y, g.z, g.w);
                    float dx1 = (P[5] + colf) * CELLSZ, dy1 = (P[6] + rowf) * CELLSZ;
                    float i1 = iou_fn(dx1, dy1, P[7], P[8], g.x, g.y, g.z, g.w);
                    float b = fmaxf(i0, i1);
                    if (b > bestv) { bestv = b; jwin = j; bj = (i0 >= i1) ? 0 : 1; }
                }
            }

            float4 g = s_box[jwin];
            float best_iou = bestv;

            float rx = bj ? P[5] : P[0];
            float ry = bj ? P[6] : P[1];
            float rw = bj ? P[7] : P[2];
            float rh = bj ? P[8] : P[3];
            float rconf = bj ? conf1 : conf0;
            float oconf = bj ? conf0 : conf1;

            float pax = (rx + colf) * CELLSZ, pay = (ry + rowf) * CELLSZ;
            float paw = fabsf(rw), pah = fabsf(rh);
            float cx_rel = g.x * (float)S_GRID - colf;
            float cy_rel = g.y * (float)S_GRID - rowf;
            float gax = (cx_rel + colf) * CELLSZ;
            float gay = (cy_rel + rowf) * CELLSZ;
            float lcoord = ciou_fn(pax, pay, paw, pah, gax, gay, g.z, g.w);

            float dobj = rconf - best_iou;

            float lcls = 0.f;
#pragma unroll
            for (int kk = 0; kk < 10; ++kk) {
                float tk = (mask >> kk) & 1u ? 1.f : 0.f;
                lcls += focal_fn(P[10 + kk], tk);
            }

            acc += 5.f * lcoord + dobj * dobj + 0.1f * (oconf * oconf) + lcls;
        }
    }

    // deterministic block reduction (once per block)
    for (int off = 32; off > 0; off >>= 1) acc += __shfl_down(acc, off);
    int lane = tid & 63, wid = tid >> 6;
    if (lane == 0) sred[wid] = acc;
    __syncthreads();
    if (tid == 0) {
        float s = 0.f;
#pragma unroll
        for (int w = 0; w < BLK / 64; ++w) s += sred[w];
        partial[bid] = s;
    }
}

// ---------- kernel 2: final reduction ----------

__global__ void reduce_kernel(const float* __restrict__ partial, float* __restrict__ out) {
    float acc = 0.f;
    for (int i = threadIdx.x; i < NBLK; i += blockDim.x) acc += partial[i];
    for (int off = 32; off > 0; off >>= 1) acc += __shfl_down(acc, off);
    __shared__ float sred[BLK / 64];
    int lane = threadIdx.x & 63, wid = threadIdx.x >> 6;
    if (lane == 0) sred[wid] = acc;
    __syncthreads();
    if (threadIdx.x == 0) {
        float s = 0.f;
#pragma unroll
        for (int w = 0; w < BLK / 64; ++w) s += sred[w];
        out[0] = s / (float)BATCH_N;
    }
}

// ---------- launcher: 2 launches ----------

extern "C" void kernel_launch(void* const* d_in, const int* in_sizes, int n_in,
                              void* d_out, int out_size, void* d_ws, size_t ws_size,
                              hipStream_t stream) {
    const float* pred = (const float*)d_in[0];
    const float* tgt  = (const float*)d_in[1];
    float* partial = (float*)d_ws;   // 4B * NBLK, fully overwritten every launch

    loss_kernel<<<NBLK, BLK, 0, stream>>>(pred, tgt, partial);
    reduce_kernel<<<1, BLK, 0, stream>>>(partial, (float*)d_out);
}

// Round 7
// 45.204 us; speedup vs baseline: 2.2538x; 2.2538x over previous
//
#include <hip/hip_runtime.h>
#include <math.h>

#define S_GRID   112
#define BATCH_N  64
#define NBOX     100
#define SS       (S_GRID * S_GRID)       // 12544 cells per image
#define NCELLS   (BATCH_N * SS)          // 802816
#define NF4      (NCELLS * 5)            // 4,014,080 float4s in pred
#define CELLSZ   (1.0f / (float)S_GRID)
#define BLK      256
#define NOBJ_BLKS 2048
#define HIT_BLKS  BATCH_N                // 1 block per image
#define HIT_THR   128
#define NPART    (NOBJ_BLKS + HIT_BLKS)  // 2112 partials

// ---------- device helpers ----------

__device__ __forceinline__ float iou_fn(float px, float py, float pw, float ph,
                                        float gx, float gy, float gw, float gh) {
    // matches reference _iou (eps = 1e-6)
    float px1 = px - pw * 0.5f, px2 = px + pw * 0.5f;
    float py1 = py - ph * 0.5f, py2 = py + ph * 0.5f;
    float gx1 = gx - gw * 0.5f, gx2 = gx + gw * 0.5f;
    float gy1 = gy - gh * 0.5f, gy2 = gy + gh * 0.5f;
    float iw = fmaxf(fminf(px2, gx2) - fmaxf(px1, gx1), 0.f);
    float ih = fmaxf(fminf(py2, gy2) - fmaxf(py1, gy1), 0.f);
    float inter = iw * ih;
    float ap = fmaxf(px2 - px1, 0.f) * fmaxf(py2 - py1, 0.f);
    float ag = fmaxf(gx2 - gx1, 0.f) * fmaxf(gy2 - gy1, 0.f);
    float uni = ap + ag - inter;
    return inter / (uni + 1e-6f);
}

__device__ __forceinline__ float ciou_fn(float px, float py, float pw, float ph,
                                         float gx, float gy, float gw, float gh) {
    // matches reference _ciou (eps = 1e-7)
    const float eps = 1e-7f;
    float px1 = px - pw * 0.5f, px2 = px + pw * 0.5f;
    float py1 = py - ph * 0.5f, py2 = py + ph * 0.5f;
    float gx1 = gx - gw * 0.5f, gx2 = gx + gw * 0.5f;
    float gy1 = gy - gh * 0.5f, gy2 = gy + gh * 0.5f;
    float iw = fmaxf(fminf(px2, gx2) - fmaxf(px1, gx1), 0.f);
    float ih = fmaxf(fminf(py2, gy2) - fmaxf(py1, gy1), 0.f);
    float inter = iw * ih;
    float ap = fmaxf(px2 - px1, 0.f) * fmaxf(py2 - py1, 0.f);
    float ag = fmaxf(gx2 - gx1, 0.f) * fmaxf(gy2 - gy1, 0.f);
    float uni = ap + ag - inter;
    float iou = inter / (uni + eps);
    float dx = px - gx, dy = py - gy;
    float rho2 = dx * dx + dy * dy;
    float cw = fmaxf(px2, gx2) - fminf(px1, gx1);
    float ch = fmaxf(py2, gy2) - fminf(py1, gy1);
    float c2 = cw * cw + ch * ch + eps;
    float dv = atanf(gw / (gh + eps)) - atanf(pw / (ph + eps));
    float v = 0.40528473456935109f * dv * dv;   // 4/pi^2
    float alpha = v / (1.f - iou + v + eps);
    return 1.f - iou + rho2 / c2 + alpha * v;
}

__device__ __forceinline__ float focal_fn(float logit, float t) {
    float bce = fmaxf(logit, 0.f) - logit * t + log1pf(expf(-fabsf(logit)));
    float p = 1.f / (1.f + expf(-logit));
    float p_t = t * p + (1.f - t) * (1.f - p);
    float a_t = t * 0.25f + (1.f - t) * 0.75f;
    float om = 1.f - p_t;
    return a_t * om * om * bce;
}

// ---------- kernel 1: pure-stream noobj conf^2 over ALL cells ----------
// pred viewed as flat float4[NF4]; cell = i/5, slot r = i%5.
// conf0 = float 4 of cell  -> r==1 component x ; conf1 = float 9 -> r==2 component y.
// Over-counts obj cells; hit_kernel subtracts the correction. No tables, no
// divergence, no LDS staging: this is the streaming roofline probe.

__global__ __launch_bounds__(BLK) void noobj_kernel(const float4* __restrict__ p4,
                                                    float* __restrict__ partial) {
    const int gid = blockIdx.x * BLK + threadIdx.x;
    const int stride = NOBJ_BLKS * BLK;      // 524288
    float acc = 0.f;
    int r = gid % 5;
    for (int i = gid; i < NF4; i += stride) {
        float4 v = p4[i];
        if (r == 1) acc += v.x * v.x;        // conf0^2
        if (r == 2) acc += v.y * v.y;        // conf1^2
        r += 3; if (r >= 5) r -= 5;          // (stride % 5 == 3)
    }
    acc *= 0.1f;

    for (int off = 32; off > 0; off >>= 1) acc += __shfl_down(acc, off);
    __shared__ float sred[BLK / 64];
    int lane = threadIdx.x & 63, wid = threadIdx.x >> 6;
    if (lane == 0) sred[wid] = acc;
    __syncthreads();
    if (threadIdx.x == 0) {
        float s = 0.f;
#pragma unroll
        for (int w = 0; w < BLK / 64; ++w) s += sred[w];
        partial[blockIdx.x] = s;
    }
}

// ---------- kernel 2: hit cells only (<=100 per image, 1 block per image) ----------

__global__ __launch_bounds__(HIT_THR) void hit_kernel(const float* __restrict__ pred,
                                                      const float* __restrict__ tgt,
                                                      float* __restrict__ partial) {
    __shared__ int      s_cell[NBOX];
    __shared__ float4   s_box[NBOX];
    __shared__ unsigned s_cbit[NBOX];

    const int img = blockIdx.x, tid = threadIdx.x;

    if (tid < NBOX) {
        const float* t = tgt + ((size_t)img * NBOX + tid) * 5;
        float t0 = t[0], cx = t[1], cy = t[2], w = t[3], h = t[4];
        int cellid = -1; unsigned cb = 0u;
        if (t0 >= 0.f) {
            int cls = min(max((int)t0, 0), 9);
            int col = min(max((int)(cx * (float)S_GRID), 0), S_GRID - 1);
            int row = min(max((int)(cy * (float)S_GRID), 0), S_GRID - 1);
            cellid = row * S_GRID + col;
            cb = 1u << cls;
        }
        s_cell[tid] = cellid;
        s_box[tid]  = make_float4(cx, cy, w, h);
        s_cbit[tid] = cb;
    }
    __syncthreads();

    float acc = 0.f;
    int mycell = (tid < NBOX) ? s_cell[tid] : -1;
    bool claim = (mycell >= 0);
    if (claim) {                      // owner = smallest box index targeting this cell
        for (int j = 0; j < tid; ++j)
            if (s_cell[j] == mycell) { claim = false; break; }
    }

    if (claim) {
        const int rc = mycell;
        const float colf = (float)(rc % S_GRID);
        const float rowf = (float)(rc / S_GRID);
        const float* P = pred + ((size_t)img * SS + rc) * 20;

        float p0 = P[0], p1 = P[1], p2 = P[2], p3 = P[3], conf0 = P[4];
        float p5 = P[5], p6 = P[6], p7 = P[7], p8 = P[8], conf1 = P[9];

        // decoded pred boxes (shared across all candidate gt boxes)
        float dx0 = (p0 + colf) * CELLSZ, dy0 = (p1 + rowf) * CELLSZ;
        float dx1 = (p5 + colf) * CELLSZ, dy1 = (p6 + rowf) * CELLSZ;

        unsigned mask = 0u; float bestv = -1.f; int jwin = 0, bj = 0;
        for (int j = 0; j < NBOX; ++j) {
            if (s_cell[j] == rc) {
                mask |= s_cbit[j];
                float4 g = s_box[j];
                float i0 = iou_fn(dx0, dy0, p2, p3, g.x, g.y, g.z, g.w);
                float i1 = iou_fn(dx1, dy1, p7, p8, g.x, g.y, g.z, g.w);
                float b = fmaxf(i0, i1);
                if (b > bestv) { bestv = b; jwin = j; bj = (i0 >= i1) ? 0 : 1; }
            }
        }

        float4 g = s_box[jwin];
        float best_iou = bestv;

        float rx = bj ? p5 : p0;
        float ry = bj ? p6 : p1;
        float rw = bj ? p7 : p2;
        float rh = bj ? p8 : p3;
        float rconf = bj ? conf1 : conf0;
        float oconf = bj ? conf0 : conf1;

        float pax = (rx + colf) * CELLSZ, pay = (ry + rowf) * CELLSZ;
        float paw = fabsf(rw), pah = fabsf(rh);
        float cx_rel = g.x * (float)S_GRID - colf;
        float cy_rel = g.y * (float)S_GRID - rowf;
        float gax = (cx_rel + colf) * CELLSZ;
        float gay = (cy_rel + rowf) * CELLSZ;
        float lcoord = ciou_fn(pax, pay, paw, pah, gax, gay, g.z, g.w);

        float dobj = rconf - best_iou;

        float lcls = 0.f;
#pragma unroll
        for (int k = 0; k < 10; ++k) {
            float tk = (mask >> k) & 1u ? 1.f : 0.f;
            lcls += focal_fn(P[10 + k], tk);
        }

        acc = 5.f * lcoord + dobj * dobj + 0.1f * (oconf * oconf) + lcls
            - 0.1f * (conf0 * conf0 + conf1 * conf1);   // undo stream over-count
    }

    // block reduction over 2 waves
    for (int off = 32; off > 0; off >>= 1) acc += __shfl_down(acc, off);
    __shared__ float sred[HIT_THR / 64];
    int lane = tid & 63, wid = tid >> 6;
    if (lane == 0) sred[wid] = acc;
    __syncthreads();
    if (tid == 0) {
        float s = 0.f;
#pragma unroll
        for (int w = 0; w < HIT_THR / 64; ++w) s += sred[w];
        partial[NOBJ_BLKS + img] = s;
    }
}

// ---------- kernel 3: final reduction ----------

__global__ void reduce_kernel(const float* __restrict__ partial, float* __restrict__ out) {
    float acc = 0.f;
    for (int i = threadIdx.x; i < NPART; i += blockDim.x) acc += partial[i];
    for (int off = 32; off > 0; off >>= 1) acc += __shfl_down(acc, off);
    __shared__ float sred[BLK / 64];
    int lane = threadIdx.x & 63, wid = threadIdx.x >> 6;
    if (lane == 0) sred[wid] = acc;
    __syncthreads();
    if (threadIdx.x == 0) {
        float s = 0.f;
#pragma unroll
        for (int w = 0; w < BLK / 64; ++w) s += sred[w];
        out[0] = s / (float)BATCH_N;
    }
}

// ---------- launcher: 3 launches, no workspace init needed ----------

extern "C" void kernel_launch(void* const* d_in, const int* in_sizes, int n_in,
                              void* d_out, int out_size, void* d_ws, size_t ws_size,
                              hipStream_t stream) {
    const float* pred = (const float*)d_in[0];
    const float* tgt  = (const float*)d_in[1];
    float* partial = (float*)d_ws;   // NPART floats, fully overwritten every launch

    noobj_kernel<<<NOBJ_BLKS, BLK, 0, stream>>>((const float4*)pred, partial);
    hit_kernel<<<HIT_BLKS, HIT_THR, 0, stream>>>(pred, tgt, partial);
    reduce_kernel<<<1, BLK, 0, stream>>>(partial, (float*)d_out);
}